// Round 1
// baseline (74.620 us; speedup 1.0000x reference)
//
#include <hip/hip_runtime.h>

#define NLOC (1024 * 1024)          // H*W per head
#define HALF_PI 1.57079632679489662f
#define THRESH 0.9f

__device__ __forceinline__ float sigmoidf_(float x) {
    return 1.0f / (1.0f + __expf(-x));
}

__global__ __launch_bounds__(256) void decode_kernel(
    const float* __restrict__ obj1, const float* __restrict__ cs1, const float* __restrict__ bb1,
    const float* __restrict__ obj2, const float* __restrict__ cs2, const float* __restrict__ bb2,
    const float* __restrict__ orients, const float* __restrict__ adims,
    float* __restrict__ out)
{
    const int VPH = NLOC / 4;                       // float4 vectors per head
    int vid = blockIdx.x * blockDim.x + threadIdx.x;
    if (vid >= 2 * VPH) return;
    int head = (vid >= VPH) ? 1 : 0;                // uniform per block (VPH % 256 == 0)
    int v = vid - head * VPH;
    int n0 = v << 2;                                // first of 4 consecutive locations

    const float* obj = head ? obj2 : obj1;
    const float* cs  = head ? cs2  : cs1;
    const float* bb  = head ? bb2  : bb1;
    float orient = orients[head];
    float d0 = adims[0], d1 = adims[1], d2 = adims[2];
    float* ob = out + (head ? (size_t)17 * NLOC : (size_t)0);

    // ---- loads (all 16B aligned, coalesced) ----
    float4 o4 = *reinterpret_cast<const float4*>(obj + n0);
    float ov[4] = { o4.x, o4.y, o4.z, o4.w };

    float bbv[7][4];
#pragma unroll
    for (int c = 0; c < 7; ++c) {
        float4 t = *reinterpret_cast<const float4*>(bb + (size_t)c * NLOC + n0);
        bbv[c][0] = t.x; bbv[c][1] = t.y; bbv[c][2] = t.z; bbv[c][3] = t.w;
    }
    float sv[8][4];
#pragma unroll
    for (int c = 0; c < 8; ++c) {
        float4 t = *reinterpret_cast<const float4*>(cs + (size_t)c * NLOC + n0);
        sv[c][0] = t.x; sv[c][1] = t.y; sv[c][2] = t.z; sv[c][3] = t.w;
    }

    // grid: i = n>>10 (same row for all 4, since n0 % 4 == 0 and W=1024), j = n & 1023
    float fi  = (float)(n0 >> 10) + 0.5f;
    float fj0 = (float)(n0 & 1023) + 0.5f;

    float bx[28];
    float sc[32];
    float om[4], mk[4];
#pragma unroll
    for (int t = 0; t < 4; ++t) {
        float m  = (ov[t] >= THRESH) ? 1.0f : 0.0f;
        float fj = fj0 + (float)t;
        bx[t * 7 + 0] = (orient + sigmoidf_(bbv[0][t]) * HALF_PI) * m;
        bx[t * 7 + 1] = (sigmoidf_(bbv[1][t]) + fi) * m;
        bx[t * 7 + 2] = (sigmoidf_(bbv[2][t]) + fj) * m;
        bx[t * 7 + 3] = sigmoidf_(bbv[3][t]) * m;
        bx[t * 7 + 4] = d0 * __expf(bbv[4][t]) * m;
        bx[t * 7 + 5] = d1 * __expf(bbv[5][t]) * m;
        bx[t * 7 + 6] = d2 * __expf(bbv[6][t]) * m;
#pragma unroll
        for (int c = 0; c < 8; ++c) sc[t * 8 + c] = sv[c][t] * m;
        om[t] = ov[t] * m;
        mk[t] = m;
    }

    // ---- stores ----
    // boxes: 28 contiguous floats at n0*7; byte offset 28*n0 is 16B-aligned (n0 % 4 == 0)
    float* pb = ob + (size_t)n0 * 7;
#pragma unroll
    for (int q = 0; q < 7; ++q)
        *reinterpret_cast<float4*>(pb + q * 4) =
            make_float4(bx[q * 4 + 0], bx[q * 4 + 1], bx[q * 4 + 2], bx[q * 4 + 3]);

    // scores: 32 contiguous floats at 7N + n0*8 (aligned)
    float* ps = ob + (size_t)7 * NLOC + (size_t)n0 * 8;
#pragma unroll
    for (int q = 0; q < 8; ++q)
        *reinterpret_cast<float4*>(ps + q * 4) =
            make_float4(sc[q * 4 + 0], sc[q * 4 + 1], sc[q * 4 + 2], sc[q * 4 + 3]);

    *reinterpret_cast<float4*>(ob + (size_t)15 * NLOC + n0) = make_float4(om[0], om[1], om[2], om[3]);
    *reinterpret_cast<float4*>(ob + (size_t)16 * NLOC + n0) = make_float4(mk[0], mk[1], mk[2], mk[3]);
}

extern "C" void kernel_launch(void* const* d_in, const int* in_sizes, int n_in,
                              void* d_out, int out_size, void* d_ws, size_t ws_size,
                              hipStream_t stream) {
    const float* obj1    = (const float*)d_in[0];
    const float* cs1     = (const float*)d_in[1];
    const float* bb1     = (const float*)d_in[2];
    const float* obj2    = (const float*)d_in[3];
    const float* cs2     = (const float*)d_in[4];
    const float* bb2     = (const float*)d_in[5];
    const float* orients = (const float*)d_in[6];
    const float* adims   = (const float*)d_in[7];
    float* out = (float*)d_out;

    const int total = 2 * (NLOC / 4);               // 524288 threads
    const int block = 256;
    const int grid  = (total + block - 1) / block;  // 2048 blocks
    decode_kernel<<<grid, block, 0, stream>>>(obj1, cs1, bb1, obj2, cs2, bb2,
                                              orients, adims, out);
}

// Round 2
// 50.678 us; speedup vs baseline: 1.4724x; 1.4724x over previous
//
#include <hip/hip_runtime.h>

#define NLOC (1024 * 1024)          // H*W per head
#define HALF_PI 1.57079632679489662f
#define THRESH 0.9f

__device__ __forceinline__ float sigmoidf_(float x) {
    return 1.0f / (1.0f + __expf(-x));
}

// Per block: 256 threads, TILE = 1024 consecutive locations of one head.
// Each thread computes 4 consecutive locations. Boxes/scores are transposed
// through LDS so all global stores are lane-contiguous float4.
__global__ __launch_bounds__(256) void decode_kernel(
    const float* __restrict__ obj1, const float* __restrict__ cs1, const float* __restrict__ bb1,
    const float* __restrict__ obj2, const float* __restrict__ cs2, const float* __restrict__ bb2,
    const float* __restrict__ orients, const float* __restrict__ adims,
    float* __restrict__ out)
{
    __shared__ float lds[8192];                     // 32 KB, reused by both phases

    const int tid   = threadIdx.x;
    const int head  = blockIdx.x >> 10;             // 1024 blocks per head (uniform)
    const int blk   = blockIdx.x & 1023;
    const int tile0 = blk << 10;                    // first location of this tile
    const int n0    = tile0 + (tid << 2);           // first of this thread's 4 locations

    const float* obj = head ? obj2 : obj1;
    const float* cs  = head ? cs2  : cs1;
    const float* bb  = head ? bb2  : bb1;
    const float orient = orients[head];
    const float d0 = adims[0], d1 = adims[1], d2 = adims[2];
    float* ob = out + (size_t)head * 17 * NLOC;

    // ---- loads (all 16B aligned, coalesced) ----
    float4 o4 = *reinterpret_cast<const float4*>(obj + n0);
    float ov[4] = { o4.x, o4.y, o4.z, o4.w };

    float bbv[7][4];
#pragma unroll
    for (int c = 0; c < 7; ++c) {
        float4 t = *reinterpret_cast<const float4*>(bb + (size_t)c * NLOC + n0);
        bbv[c][0] = t.x; bbv[c][1] = t.y; bbv[c][2] = t.z; bbv[c][3] = t.w;
    }
    float sv[8][4];
#pragma unroll
    for (int c = 0; c < 8; ++c) {
        float4 t = *reinterpret_cast<const float4*>(cs + (size_t)c * NLOC + n0);
        sv[c][0] = t.x; sv[c][1] = t.y; sv[c][2] = t.z; sv[c][3] = t.w;
    }

    // grid coords: all 4 locations share a row (n0 % 4 == 0, W = 1024)
    const float fi  = (float)(n0 >> 10) + 0.5f;
    const float fj0 = (float)(n0 & 1023) + 0.5f;

    float mk_[4];
    float bx[28];
#pragma unroll
    for (int t = 0; t < 4; ++t) {
        float m  = (ov[t] >= THRESH) ? 1.0f : 0.0f;
        mk_[t] = m;
        float fj = fj0 + (float)t;
        bx[t * 7 + 0] = (orient + sigmoidf_(bbv[0][t]) * HALF_PI) * m;
        bx[t * 7 + 1] = (sigmoidf_(bbv[1][t]) + fi) * m;
        bx[t * 7 + 2] = (sigmoidf_(bbv[2][t]) + fj) * m;
        bx[t * 7 + 3] = sigmoidf_(bbv[3][t]) * m;
        bx[t * 7 + 4] = d0 * __expf(bbv[4][t]) * m;
        bx[t * 7 + 5] = d1 * __expf(bbv[5][t]) * m;
        bx[t * 7 + 6] = d2 * __expf(bbv[6][t]) * m;
    }

    // ---- direct stores (already coalesced): obj, mask ----
    *reinterpret_cast<float4*>(ob + (size_t)15 * NLOC + n0) =
        make_float4(ov[0] * mk_[0], ov[1] * mk_[1], ov[2] * mk_[2], ov[3] * mk_[3]);
    *reinterpret_cast<float4*>(ob + (size_t)16 * NLOC + n0) =
        make_float4(mk_[0], mk_[1], mk_[2], mk_[3]);

    // ---- phase A: boxes via LDS transpose ----
    // write: thread tid -> words [tid*28, tid*28+28); stride 28 words is
    // conflict-free per 16-lane phase (2 words/bank).
#pragma unroll
    for (int q = 0; q < 7; ++q)
        *reinterpret_cast<float4*>(&lds[tid * 28 + q * 4]) =
            make_float4(bx[q * 4 + 0], bx[q * 4 + 1], bx[q * 4 + 2], bx[q * 4 + 3]);
    __syncthreads();
    // read + store: 7168 contiguous words, fully coalesced float4
    {
        float* gb = ob + (size_t)tile0 * 7;
#pragma unroll
        for (int q = 0; q < 7; ++q) {
            int w = 4 * (tid + 256 * q);
            *reinterpret_cast<float4*>(gb + w) = *reinterpret_cast<const float4*>(&lds[w]);
        }
    }
    __syncthreads();

    // ---- phase B: scores via LDS transpose (XOR-swizzled: raw stride-32
    // writes would be a 16-way bank conflict) ----
#pragma unroll
    for (int q = 0; q < 8; ++q) {
        int t = q >> 1, c0 = (q & 1) * 4;
        float m = mk_[t];
        int f = tid * 8 + q;                 // logical float4 index
        int p = f ^ ((f >> 3) & 7);          // swizzled physical index
        *reinterpret_cast<float4*>(&lds[p * 4]) =
            make_float4(sv[c0][t] * m, sv[c0 + 1][t] * m, sv[c0 + 2][t] * m, sv[c0 + 3][t] * m);
    }
    __syncthreads();
    {
        float* gs = ob + (size_t)7 * NLOC + (size_t)tile0 * 8;
#pragma unroll
        for (int q = 0; q < 8; ++q) {
            int f = tid + 256 * q;           // logical float4 index (contiguous out)
            int p = f ^ ((f >> 3) & 7);
            *reinterpret_cast<float4*>(gs + 4 * f) =
                *reinterpret_cast<const float4*>(&lds[p * 4]);
        }
    }
}

extern "C" void kernel_launch(void* const* d_in, const int* in_sizes, int n_in,
                              void* d_out, int out_size, void* d_ws, size_t ws_size,
                              hipStream_t stream) {
    const float* obj1    = (const float*)d_in[0];
    const float* cs1     = (const float*)d_in[1];
    const float* bb1     = (const float*)d_in[2];
    const float* obj2    = (const float*)d_in[3];
    const float* cs2     = (const float*)d_in[4];
    const float* bb2     = (const float*)d_in[5];
    const float* orients = (const float*)d_in[6];
    const float* adims   = (const float*)d_in[7];
    float* out = (float*)d_out;

    decode_kernel<<<2048, 256, 0, stream>>>(obj1, cs1, bb1, obj2, cs2, bb2,
                                            orients, adims, out);
}